// Round 1
// 451.155 us; speedup vs baseline: 1.6951x; 1.6951x over previous
//
#include <hip/hip_runtime.h>
#include <hip/hip_bf16.h>

// BinTreeNetwork (ALL TENSORS FP32):
//   out[B, o] = out0[o] + out_bias[o]
//             + sum_{i=0}^{20} res_i[B mod 2^{i+1}, :] . out_layers[i][o, :]
// res tables (2^{i+1} rows x 2 cols, fp32) for levels 0..16 in ws;
// levels 17..20 computed on the fly in k_final via two register chains
// from the two level-16 ancestor rows (b<<16)|(B&0xFFFF).
//   res_j[m,k'] = sum_k res_{j-1}[src,k] * W_s(layer j-1)[k',k] + b_s[k']
//   src = ((m>>j)<<(j-1)) | (m & (2^{j-1}-1)),  s = (m>>(j-1))&1  (drop 2nd-MSB)
//
// ws layout (fp32 elements):
//   [0, 2^19-4)  res tables, level i at (1<<(i+2))-4
//   P0 = 1<<19:
//     +0      base[32]     = out0.x + out_bias
//     +32     outLf[21*64] = out_layers copy
//     +1376   tLf[84], +1460 tRf[84], +1544 tLbf[42], +1586 tRbf[42]
//     +2048   C7[256*32]   = base + levels 0..7 pre-folded
// total ws: (2^19 + 10240)*4 B ~= 2.14 MB

#define P0 (1u << 19)

typedef float floatx4 __attribute__((ext_vector_type(4)));

// ---------------- K1: seed + levels 1..13 + param copy + C7 (1 block) --------
__global__ __launch_bounds__(1024) void k_prefix(
    const float* __restrict__ x,
    const float* __restrict__ inL,
    const float* __restrict__ inR,
    const float* __restrict__ inLb,
    const float* __restrict__ inRb,
    const float* __restrict__ treeL,
    const float* __restrict__ treeR,
    const float* __restrict__ treeLb,
    const float* __restrict__ treeRb,
    const float* __restrict__ outL0,
    const float* __restrict__ outLs,
    const float* __restrict__ outB,
    float* __restrict__ ws)
{
    __shared__ float xs[4096];
    __shared__ float dots[36];
    const int tid = threadIdx.x;

    for (int i = tid; i < 4096; i += 1024) xs[i] = x[i];
    __syncthreads();

    const int wave = tid >> 6, lane = tid & 63;
    for (int d = wave; d < 36; d += 16) {
        const float* row =
            (d < 2) ? inL + d * 4096 :
            (d < 4) ? inR + (d - 2) * 4096 :
                      outL0 + (d - 4) * 4096;
        float s = 0.f;
        for (int k = lane; k < 4096; k += 64) s += row[k] * xs[k];
        #pragma unroll
        for (int off = 32; off; off >>= 1) s += __shfl_down(s, off, 64);
        if (lane == 0) dots[d] = s;
    }
    __syncthreads();

    float* base  = ws + P0;
    float* outLf = ws + P0 + 32;
    float* tLf   = ws + P0 + 1376;
    float* tRf   = ws + P0 + 1460;
    float* tLbf  = ws + P0 + 1544;
    float* tRbf  = ws + P0 + 1586;
    float* C7    = ws + P0 + 2048;

    for (int i = tid; i < 21 * 64; i += 1024) outLf[i] = outLs[i];
    if (tid < 84)                      tLf[tid]        = treeL[tid];
    else if (tid < 168)                tRf[tid - 84]   = treeR[tid - 84];
    else if (tid < 210)                tLbf[tid - 168] = treeLb[tid - 168];
    else if (tid < 252)                tRbf[tid - 210] = treeRb[tid - 210];
    if (tid < 32) base[tid] = dots[4 + tid] + outB[tid];
    if (tid < 2) {
        // res_0 row j = {left0[j], right0[j]}
        ws[tid * 2 + 0] = dots[tid]     + inLb[tid];
        ws[tid * 2 + 1] = dots[2 + tid] + inRb[tid];
    }
    __syncthreads();

    // levels 1..13
    for (int i = 1; i <= 13; ++i) {
        const float* prev = ws + ((1u << (i + 1)) - 4);
        float* cur        = ws + ((1u << (i + 2)) - 4);
        const int rows = 1 << (i + 1);
        const int lowmask = (1 << (i - 1)) - 1;
        for (int m = tid; m < rows; m += 1024) {
            const int src = ((m >> i) << (i - 1)) | (m & lowmask);
            const int s = (m >> (i - 1)) & 1;
            const float* W  = (s ? tRf  : tLf)  + (i - 1) * 4;
            const float* bb = (s ? tRbf : tLbf) + (i - 1) * 2;
            const float p0 = prev[src * 2], p1 = prev[src * 2 + 1];
            cur[m * 2 + 0] = W[0] * p0 + W[1] * p1 + bb[0];
            cur[m * 2 + 1] = W[2] * p0 + W[3] * p1 + bb[1];
        }
        __syncthreads();
    }

    // C7[m][o] = base[o] + sum_{i=0}^{7} res_i[m mod 2^{i+1}] . outL[i][o]
    for (int idx = tid; idx < 8192; idx += 1024) {
        const int m = idx >> 5, o = idx & 31;
        float s = base[o];
        #pragma unroll
        for (int i = 0; i < 8; ++i) {
            const float* ri = ws + ((1u << (i + 2)) - 4) + (m & ((2 << i) - 1)) * 2;
            s += ri[0] * outLf[i * 64 + o * 2] + ri[1] * outLf[i * 64 + o * 2 + 1];
        }
        C7[idx] = s;
    }
}

// ---------------- K2: levels 14..16 via per-block register chains from res_13 -
__global__ __launch_bounds__(256) void k_mid(float* __restrict__ ws)
{
    const int blk = blockIdx.x;
    int j, b;
    if      (blk < 16) { j = 14; b = blk; }
    else if (blk < 48) { j = 15; b = blk - 16; }
    else               { j = 16; b = blk - 48; }

    const float* tLf  = ws + P0 + 1376;
    const float* tRf  = ws + P0 + 1460;
    const float* tLbf = ws + P0 + 1544;
    const float* tRbf = ws + P0 + 1586;

    // walk base row from level j down to 13, recording per-level select bits
    unsigned m = (unsigned)b << 11;
    const unsigned basej = m;
    unsigned sbits = 0;
    for (int l = j; l > 13; --l) {
        sbits |= ((m >> (l - 1)) & 1u) << l;
        m = ((m >> l) << (l - 1)) | (m & ((1u << (l - 1)) - 1));
    }

    // this thread's 8 rows of res_13 (aligned float4 x4)
    const int r0 = threadIdx.x * 8;
    const floatx4* s4 = (const floatx4*)(ws + ((1u << 15) - 4) + (m + r0) * 2);
    floatx4 a0 = s4[0], a1 = s4[1], a2 = s4[2], a3 = s4[3];
    float r[8][2] = {{a0.x,a0.y},{a0.z,a0.w},{a1.x,a1.y},{a1.z,a1.w},
                     {a2.x,a2.y},{a2.z,a2.w},{a3.x,a3.y},{a3.z,a3.w}};

    for (int l = 14; l <= j; ++l) {
        const int s = (sbits >> l) & 1;
        const float* W  = (s ? tRf  : tLf)  + (l - 1) * 4;
        const float* bb = (s ? tRbf : tLbf) + (l - 1) * 2;
        const float w00 = W[0], w01 = W[1], w10 = W[2], w11 = W[3];
        const float b0 = bb[0], b1 = bb[1];
        #pragma unroll
        for (int q = 0; q < 8; ++q) {
            const float p0 = r[q][0], p1 = r[q][1];
            r[q][0] = w00 * p0 + w01 * p1 + b0;
            r[q][1] = w10 * p0 + w11 * p1 + b1;
        }
    }

    floatx4* d4 = (floatx4*)(ws + ((1u << (j + 2)) - 4) + (basej + r0) * 2);
    d4[0] = (floatx4){r[0][0], r[0][1], r[1][0], r[1][1]};
    d4[1] = (floatx4){r[2][0], r[2][1], r[3][0], r[3][1]};
    d4[2] = (floatx4){r[4][0], r[4][1], r[5][0], r[5][1]};
    d4[3] = (floatx4){r[6][0], r[6][1], r[7][0], r[7][1]};
}

// ---------------- K3: final gather-sum, 1 thread per leaf --------------------
// Store path: accumulators are transposed through LDS (XOR-swizzled,
// bank-conflict-free both phases) so every wave store instruction covers a
// contiguous aligned 1 KiB (16 B/lane x 64 lanes) -> full-line nontemporal
// writes, 1.0x HBM write amplification (was 3.46x with 128 B-strided 16 B
// stores under nt no-allocate).
__global__ __launch_bounds__(256) void k_final(const float* __restrict__ ws,
                                               float* __restrict__ out)
{
    __shared__ floatx4 st[256 * 8];   // 32 KiB
    const int tid = threadIdx.x;
    const unsigned B = blockIdx.x * 256u + tid;
    const float* outLf = ws + P0 + 32;
    const float* tLf   = ws + P0 + 1376;
    const float* tRf   = ws + P0 + 1460;
    const float* tLbf  = ws + P0 + 1544;
    const float* tRbf  = ws + P0 + 1586;
    const float* C7    = ws + P0 + 2048;

    float acc[32];
    {   // C7 row (contiguous 128 B, 16B-aligned)
        const floatx4* c4 = (const floatx4*)(C7 + (B & 255u) * 32);
        #pragma unroll
        for (int q = 0; q < 8; ++q) {
            floatx4 v = c4[q];
            acc[q * 4 + 0] = v.x; acc[q * 4 + 1] = v.y;
            acc[q * 4 + 2] = v.z; acc[q * 4 + 3] = v.w;
        }
    }

    // levels 8..15 from tables
    float p[8][2];
    #pragma unroll
    for (int i = 8; i <= 15; ++i) {
        const float2* ri = (const float2*)(ws + ((1u << (i + 2)) - 4)
                                              + (B & ((2u << i) - 1)) * 2);
        float2 v = *ri;
        p[i - 8][0] = v.x;
        p[i - 8][1] = v.y;
    }
    #pragma unroll
    for (int i = 0; i < 8; ++i) {
        const float* cf = outLf + (i + 8) * 64;   // uniform -> scalar loads
        const float q0 = p[i][0], q1 = p[i][1];
        #pragma unroll
        for (int o = 0; o < 32; ++o)
            acc[o] += q0 * cf[o * 2] + q1 * cf[o * 2 + 1];
    }

    // levels 16..20: two register chains from the two level-16 ancestor rows
    // ancestor at level 16 of contribution-level l's row = (B_l<<16)|(B&0xFFFF);
    // shared select bits s_j = B_{j-1}; contribution l picks chain B_l.
    {
        const unsigned Blo = B & 0xFFFFu;
        const float* r16 = ws + ((1u << 18) - 4);
        const float2* rA = (const float2*)(r16 + Blo * 2);
        const float2* rC = (const float2*)(r16 + (Blo + 65536u) * 2);
        float2 vA = *rA, vC = *rC;
        float A0 = vA.x, A1 = vA.y;   // MSB=0 chain
        float c0 = vC.x, c1 = vC.y;   // MSB=1 chain
        {   // level 16 contribution
            const int pick = (B >> 16) & 1;
            const float q0 = pick ? c0 : A0, q1 = pick ? c1 : A1;
            const float* cf = outLf + 16 * 64;
            #pragma unroll
            for (int o = 0; o < 32; ++o)
                acc[o] += q0 * cf[o * 2] + q1 * cf[o * 2 + 1];
        }
        #pragma unroll
        for (int l = 17; l <= 20; ++l) {
            const int s = (B >> (l - 1)) & 1;
            const float* WL = tLf + (l - 1) * 4;   // uniform -> scalar loads
            const float* WR = tRf + (l - 1) * 4;
            const float* bL = tLbf + (l - 1) * 2;
            const float* bR = tRbf + (l - 1) * 2;
            const float w00 = s ? WR[0] : WL[0], w01 = s ? WR[1] : WL[1];
            const float w10 = s ? WR[2] : WL[2], w11 = s ? WR[3] : WL[3];
            const float b0  = s ? bR[0] : bL[0], b1  = s ? bR[1] : bL[1];
            const float nA0 = w00 * A0 + w01 * A1 + b0;
            const float nA1 = w10 * A0 + w11 * A1 + b1;
            const float nc0 = w00 * c0 + w01 * c1 + b0;
            const float nc1 = w10 * c0 + w11 * c1 + b1;
            A0 = nA0; A1 = nA1; c0 = nc0; c1 = nc1;
            const int pick = (B >> l) & 1;
            const float q0 = pick ? c0 : A0, q1 = pick ? c1 : A1;
            const float* cf = outLf + l * 64;
            #pragma unroll
            for (int o = 0; o < 32; ++o)
                acc[o] += q0 * cf[o * 2] + q1 * cf[o * 2 + 1];
        }
    }

    // ---- transpose through LDS, then fully-coalesced 1 KiB/instr nt stores --
    // write: thread t, chunk q (16 B) -> st[t*8 + (q ^ (t&7))]
    //   banks per instr: group (q ^ (t&7)) -> 8 lanes per 4-bank group: free
    #pragma unroll
    for (int q = 0; q < 8; ++q) {
        st[tid * 8 + (q ^ (tid & 7))] =
            (floatx4){acc[q * 4 + 0], acc[q * 4 + 1],
                      acc[q * 4 + 2], acc[q * 4 + 3]};
    }
    __syncthreads();

    // read: wave w, instr j -> global bytes [blk*32768 + w*8192 + j*1024, +1024)
    //   lane provides chunk c = lane&7 of local leaf m = w*64 + j*8 + (lane>>3)
    //   LDS idx = m*8 + (c ^ (m&7));  m&7 == lane>>3  -> group (c ^ lane>>3): free
    {
        const int w = tid >> 6, lane = tid & 63;
        const int x = (lane & 7) ^ (lane >> 3);
        floatx4* dst = (floatx4*)(out + (size_t)blockIdx.x * 8192u
                                      + (unsigned)w * 2048u + (unsigned)lane * 4u);
        #pragma unroll
        for (int j = 0; j < 8; ++j) {
            const int m = w * 64 + j * 8 + (lane >> 3);
            __builtin_nontemporal_store(st[m * 8 + x], dst + j * 64);
        }
    }
}

extern "C" void kernel_launch(void* const* d_in, const int* in_sizes, int n_in,
                              void* d_out, int out_size, void* d_ws, size_t ws_size,
                              hipStream_t stream) {
    const float* x     = (const float*)d_in[0];
    const float* inL   = (const float*)d_in[1];
    const float* inR   = (const float*)d_in[2];
    const float* inLb  = (const float*)d_in[3];
    const float* inRb  = (const float*)d_in[4];
    const float* treeL = (const float*)d_in[5];
    const float* treeR = (const float*)d_in[6];
    const float* treeLb= (const float*)d_in[7];
    const float* treeRb= (const float*)d_in[8];
    const float* outL0 = (const float*)d_in[9];
    const float* outLs = (const float*)d_in[10];
    const float* outB  = (const float*)d_in[11];
    float* ws = (float*)d_ws;
    float* out = (float*)d_out;

    hipLaunchKernelGGL(k_prefix, dim3(1), dim3(1024), 0, stream,
                       x, inL, inR, inLb, inRb, treeL, treeR, treeLb, treeRb,
                       outL0, outLs, outB, ws);
    hipLaunchKernelGGL(k_mid, dim3(112), dim3(256), 0, stream, ws);
    hipLaunchKernelGGL(k_final, dim3(1u << 13), dim3(256), 0, stream, ws, out);
}

// Round 2
// 379.685 us; speedup vs baseline: 2.0142x; 1.1882x over previous
//
#include <hip/hip_runtime.h>
#include <hip/hip_bf16.h>

// BinTreeNetwork (ALL TENSORS FP32):
//   out[B, o] = out0[o] + out_bias[o]
//             + sum_{i=0}^{20} res_i[B mod 2^{i+1}, :] . out_layers[i][o, :]
// res tables (2^{i+1} rows x 2 cols, fp32) for levels 0..16 in ws;
// levels 17..20 computed on the fly in k_final via two register chains
// from the two level-16 ancestor rows (b<<16)|(B&0xFFFF).
//   res_j[m,k'] = sum_k res_{j-1}[src,k] * W_s(layer j-1)[k',k] + b_s[k']
//   src = ((m>>j)<<(j-1)) | (m & (2^{j-1}-1)),  s = (m>>(j-1))&1  (drop 2nd-MSB)
//
// ws layout (fp32 elements):
//   [0, 2^19-4)  res tables, level i at (1<<(i+2))-4
//   P0 = 1<<19:
//     +0      base[32]     = out0.x + out_bias
//     +32     outLf[21*64] = out_layers copy
//     +1376   tLf[84], +1460 tRf[84], +1544 tLbf[42], +1586 tRbf[42]
//     +2048   C7[256*32]   = base + levels 0..7 pre-folded
//   C14OFF = 1<<20 (byte 4 MB): C14[2^15][32] = C7 + levels 8..14 pre-folded
//            (only used when ws_size >= 8 MB; else legacy k_final path)
// total ws (fold path): 8 MB

#define P0 (1u << 19)
#define C14OFF (1u << 20)

typedef float floatx4 __attribute__((ext_vector_type(4)));

// ---------------- K1: seed + levels 1..13 + param copy + C7 (1 block) --------
__global__ __launch_bounds__(1024) void k_prefix(
    const float* __restrict__ x,
    const float* __restrict__ inL,
    const float* __restrict__ inR,
    const float* __restrict__ inLb,
    const float* __restrict__ inRb,
    const float* __restrict__ treeL,
    const float* __restrict__ treeR,
    const float* __restrict__ treeLb,
    const float* __restrict__ treeRb,
    const float* __restrict__ outL0,
    const float* __restrict__ outLs,
    const float* __restrict__ outB,
    float* __restrict__ ws)
{
    __shared__ float xs[4096];
    __shared__ float dots[36];
    const int tid = threadIdx.x;

    // stage x as float4 (rows are 16 KB-aligned)
    if (tid < 1024)
        ((floatx4*)xs)[tid] = ((const floatx4*)x)[tid];
    __syncthreads();

    const int wave = tid >> 6, lane = tid & 63;
    for (int d = wave; d < 36; d += 16) {
        const float* row =
            (d < 2) ? inL + d * 4096 :
            (d < 4) ? inR + (d - 2) * 4096 :
                      outL0 + (d - 4) * 4096;
        const floatx4* r4 = (const floatx4*)row;
        const floatx4* x4 = (const floatx4*)xs;
        float s = 0.f;
        for (int k = lane; k < 1024; k += 64) {
            floatx4 a = r4[k], b = x4[k];
            s += a.x * b.x + a.y * b.y + a.z * b.z + a.w * b.w;
        }
        #pragma unroll
        for (int off = 32; off; off >>= 1) s += __shfl_down(s, off, 64);
        if (lane == 0) dots[d] = s;
    }
    __syncthreads();

    float* base  = ws + P0;
    float* outLf = ws + P0 + 32;
    float* tLf   = ws + P0 + 1376;
    float* tRf   = ws + P0 + 1460;
    float* tLbf  = ws + P0 + 1544;
    float* tRbf  = ws + P0 + 1586;
    float* C7    = ws + P0 + 2048;

    for (int i = tid; i < 21 * 64; i += 1024) outLf[i] = outLs[i];
    if (tid < 84)                      tLf[tid]        = treeL[tid];
    else if (tid < 168)                tRf[tid - 84]   = treeR[tid - 84];
    else if (tid < 210)                tLbf[tid - 168] = treeLb[tid - 168];
    else if (tid < 252)                tRbf[tid - 210] = treeRb[tid - 210];
    if (tid < 32) base[tid] = dots[4 + tid] + outB[tid];
    if (tid < 2) {
        // res_0 row j = {left0[j], right0[j]}
        ws[tid * 2 + 0] = dots[tid]     + inLb[tid];
        ws[tid * 2 + 1] = dots[2 + tid] + inRb[tid];
    }
    __syncthreads();

    // levels 1..13
    for (int i = 1; i <= 13; ++i) {
        const float* prev = ws + ((1u << (i + 1)) - 4);
        float* cur        = ws + ((1u << (i + 2)) - 4);
        const int rows = 1 << (i + 1);
        const int lowmask = (1 << (i - 1)) - 1;
        for (int m = tid; m < rows; m += 1024) {
            const int src = ((m >> i) << (i - 1)) | (m & lowmask);
            const int s = (m >> (i - 1)) & 1;
            const float* W  = (s ? tRf  : tLf)  + (i - 1) * 4;
            const float* bb = (s ? tRbf : tLbf) + (i - 1) * 2;
            const float p0 = prev[src * 2], p1 = prev[src * 2 + 1];
            cur[m * 2 + 0] = W[0] * p0 + W[1] * p1 + bb[0];
            cur[m * 2 + 1] = W[2] * p0 + W[3] * p1 + bb[1];
        }
        __syncthreads();
    }

    // C7[m][o] = base[o] + sum_{i=0}^{7} res_i[m mod 2^{i+1}] . outL[i][o]
    for (int idx = tid; idx < 8192; idx += 1024) {
        const int m = idx >> 5, o = idx & 31;
        float s = base[o];
        #pragma unroll
        for (int i = 0; i < 8; ++i) {
            const float* ri = ws + ((1u << (i + 2)) - 4) + (m & ((2 << i) - 1)) * 2;
            s += ri[0] * outLf[i * 64 + o * 2] + ri[1] * outLf[i * 64 + o * 2 + 1];
        }
        C7[idx] = s;
    }
}

// ---------------- K2: levels 14..16 via per-block register chains from res_13 -
__global__ __launch_bounds__(256) void k_mid(float* __restrict__ ws)
{
    const int blk = blockIdx.x;
    int j, b;
    if      (blk < 16) { j = 14; b = blk; }
    else if (blk < 48) { j = 15; b = blk - 16; }
    else               { j = 16; b = blk - 48; }

    const float* tLf  = ws + P0 + 1376;
    const float* tRf  = ws + P0 + 1460;
    const float* tLbf = ws + P0 + 1544;
    const float* tRbf = ws + P0 + 1586;

    // walk base row from level j down to 13, recording per-level select bits
    unsigned m = (unsigned)b << 11;
    const unsigned basej = m;
    unsigned sbits = 0;
    for (int l = j; l > 13; --l) {
        sbits |= ((m >> (l - 1)) & 1u) << l;
        m = ((m >> l) << (l - 1)) | (m & ((1u << (l - 1)) - 1));
    }

    // this thread's 8 rows of res_13 (aligned float4 x4)
    const int r0 = threadIdx.x * 8;
    const floatx4* s4 = (const floatx4*)(ws + ((1u << 15) - 4) + (m + r0) * 2);
    floatx4 a0 = s4[0], a1 = s4[1], a2 = s4[2], a3 = s4[3];
    float r[8][2] = {{a0.x,a0.y},{a0.z,a0.w},{a1.x,a1.y},{a1.z,a1.w},
                     {a2.x,a2.y},{a2.z,a2.w},{a3.x,a3.y},{a3.z,a3.w}};

    for (int l = 14; l <= j; ++l) {
        const int s = (sbits >> l) & 1;
        const float* W  = (s ? tRf  : tLf)  + (l - 1) * 4;
        const float* bb = (s ? tRbf : tLbf) + (l - 1) * 2;
        const float w00 = W[0], w01 = W[1], w10 = W[2], w11 = W[3];
        const float b0 = bb[0], b1 = bb[1];
        #pragma unroll
        for (int q = 0; q < 8; ++q) {
            const float p0 = r[q][0], p1 = r[q][1];
            r[q][0] = w00 * p0 + w01 * p1 + b0;
            r[q][1] = w10 * p0 + w11 * p1 + b1;
        }
    }

    floatx4* d4 = (floatx4*)(ws + ((1u << (j + 2)) - 4) + (basej + r0) * 2);
    d4[0] = (floatx4){r[0][0], r[0][1], r[1][0], r[1][1]};
    d4[1] = (floatx4){r[2][0], r[2][1], r[3][0], r[3][1]};
    d4[2] = (floatx4){r[4][0], r[4][1], r[5][0], r[5][1]};
    d4[3] = (floatx4){r[6][0], r[6][1], r[7][0], r[7][1]};
}

// ---------------- K2b: fold levels 8..14 into C14[2^15][32] ------------------
// C14[m] = C7[m&255] + sum_{i=8..14} res_i[m mod 2^{i+1}] . outL[i]
// 4 MB table, built once (~3 us), L2-resident, read coalesced by k_final.
__global__ __launch_bounds__(256) void k_c14(float* __restrict__ ws)
{
    const unsigned m = blockIdx.x * 256u + threadIdx.x;   // 2^15 threads
    const float* outLf = ws + P0 + 32;
    const float* C7    = ws + P0 + 2048;

    float acc[32];
    const floatx4* c4 = (const floatx4*)(C7 + (m & 255u) * 32);
    #pragma unroll
    for (int q = 0; q < 8; ++q) {
        floatx4 v = c4[q];
        acc[q * 4 + 0] = v.x; acc[q * 4 + 1] = v.y;
        acc[q * 4 + 2] = v.z; acc[q * 4 + 3] = v.w;
    }
    #pragma unroll
    for (int i = 8; i <= 14; ++i) {
        const float2 v = *(const float2*)(ws + ((1u << (i + 2)) - 4)
                                             + (m & ((2u << i) - 1)) * 2);
        const float* cf = outLf + i * 64;
        #pragma unroll
        for (int o = 0; o < 32; ++o)
            acc[o] += v.x * cf[o * 2] + v.y * cf[o * 2 + 1];
    }
    floatx4* dst = (floatx4*)(ws + C14OFF + m * 32);
    #pragma unroll
    for (int q = 0; q < 8; ++q)
        dst[q] = (floatx4){acc[q * 4 + 0], acc[q * 4 + 1],
                           acc[q * 4 + 2], acc[q * 4 + 3]};
}

// ---------------- K3: final gather-sum (C14-fold path) -----------------------
// Per leaf: C14 row (coalesced 8 KB/wave from L2) + level 15 + level 16 +
// register chains 17..20  (~420 FMA/leaf vs 860 in legacy).
// Store path: LDS transpose (XOR-swizzled, conflict-free) -> contiguous
// 1 KiB-per-instruction nontemporal stores, 1.0x write amplification.
__global__ __launch_bounds__(256) void k_final_fold(const float* __restrict__ ws,
                                                    float* __restrict__ out)
{
    __shared__ floatx4 st[256 * 8];   // 32 KiB
    const int tid = threadIdx.x;
    const unsigned B = blockIdx.x * 256u + tid;
    const float* outLf = ws + P0 + 32;
    const float* tLf   = ws + P0 + 1376;
    const float* tRf   = ws + P0 + 1460;
    const float* tLbf  = ws + P0 + 1544;
    const float* tRbf  = ws + P0 + 1586;
    const float* C14   = ws + C14OFF;

    float acc[32];
    {   // C14 row (contiguous 128 B, 16B-aligned; wave reads 8 KB contiguous)
        const floatx4* c4 = (const floatx4*)(C14 + (B & 0x7FFFu) * 32);
        #pragma unroll
        for (int q = 0; q < 8; ++q) {
            floatx4 v = c4[q];
            acc[q * 4 + 0] = v.x; acc[q * 4 + 1] = v.y;
            acc[q * 4 + 2] = v.z; acc[q * 4 + 3] = v.w;
        }
    }

    // level 15 from table
    {
        const float2 v = *(const float2*)(ws + ((1u << 17) - 4)
                                             + (B & 0xFFFFu) * 2);
        const float* cf = outLf + 15 * 64;
        #pragma unroll
        for (int o = 0; o < 32; ++o)
            acc[o] += v.x * cf[o * 2] + v.y * cf[o * 2 + 1];
    }

    // levels 16..20: two register chains from the two level-16 ancestor rows
    {
        const unsigned Blo = B & 0xFFFFu;
        const float* r16 = ws + ((1u << 18) - 4);
        const float2* rA = (const float2*)(r16 + Blo * 2);
        const float2* rC = (const float2*)(r16 + (Blo + 65536u) * 2);
        float2 vA = *rA, vC = *rC;
        float A0 = vA.x, A1 = vA.y;   // MSB=0 chain
        float c0 = vC.x, c1 = vC.y;   // MSB=1 chain
        {   // level 16 contribution
            const int pick = (B >> 16) & 1;
            const float q0 = pick ? c0 : A0, q1 = pick ? c1 : A1;
            const float* cf = outLf + 16 * 64;
            #pragma unroll
            for (int o = 0; o < 32; ++o)
                acc[o] += q0 * cf[o * 2] + q1 * cf[o * 2 + 1];
        }
        #pragma unroll
        for (int l = 17; l <= 20; ++l) {
            const int s = (B >> (l - 1)) & 1;
            const float* WL = tLf + (l - 1) * 4;   // uniform -> scalar loads
            const float* WR = tRf + (l - 1) * 4;
            const float* bL = tLbf + (l - 1) * 2;
            const float* bR = tRbf + (l - 1) * 2;
            const float w00 = s ? WR[0] : WL[0], w01 = s ? WR[1] : WL[1];
            const float w10 = s ? WR[2] : WL[2], w11 = s ? WR[3] : WL[3];
            const float b0  = s ? bR[0] : bL[0], b1  = s ? bR[1] : bL[1];
            const float nA0 = w00 * A0 + w01 * A1 + b0;
            const float nA1 = w10 * A0 + w11 * A1 + b1;
            const float nc0 = w00 * c0 + w01 * c1 + b0;
            const float nc1 = w10 * c0 + w11 * c1 + b1;
            A0 = nA0; A1 = nA1; c0 = nc0; c1 = nc1;
            const int pick = (B >> l) & 1;
            const float q0 = pick ? c0 : A0, q1 = pick ? c1 : A1;
            const float* cf = outLf + l * 64;
            #pragma unroll
            for (int o = 0; o < 32; ++o)
                acc[o] += q0 * cf[o * 2] + q1 * cf[o * 2 + 1];
        }
    }

    // ---- transpose through LDS, then fully-coalesced 1 KiB/instr nt stores --
    #pragma unroll
    for (int q = 0; q < 8; ++q) {
        st[tid * 8 + (q ^ (tid & 7))] =
            (floatx4){acc[q * 4 + 0], acc[q * 4 + 1],
                      acc[q * 4 + 2], acc[q * 4 + 3]};
    }
    __syncthreads();
    {
        const int w = tid >> 6, lane = tid & 63;
        const int x = (lane & 7) ^ (lane >> 3);
        floatx4* dst = (floatx4*)(out + (size_t)blockIdx.x * 8192u
                                      + (unsigned)w * 2048u + (unsigned)lane * 4u);
        #pragma unroll
        for (int j = 0; j < 8; ++j) {
            const int m = w * 64 + j * 8 + (lane >> 3);
            __builtin_nontemporal_store(st[m * 8 + x], dst + j * 64);
        }
    }
}

// ---------------- K3 (legacy, no C14): verified round-1 kernel ---------------
__global__ __launch_bounds__(256) void k_final_legacy(const float* __restrict__ ws,
                                                      float* __restrict__ out)
{
    __shared__ floatx4 st[256 * 8];
    const int tid = threadIdx.x;
    const unsigned B = blockIdx.x * 256u + tid;
    const float* outLf = ws + P0 + 32;
    const float* tLf   = ws + P0 + 1376;
    const float* tRf   = ws + P0 + 1460;
    const float* tLbf  = ws + P0 + 1544;
    const float* tRbf  = ws + P0 + 1586;
    const float* C7    = ws + P0 + 2048;

    float acc[32];
    {
        const floatx4* c4 = (const floatx4*)(C7 + (B & 255u) * 32);
        #pragma unroll
        for (int q = 0; q < 8; ++q) {
            floatx4 v = c4[q];
            acc[q * 4 + 0] = v.x; acc[q * 4 + 1] = v.y;
            acc[q * 4 + 2] = v.z; acc[q * 4 + 3] = v.w;
        }
    }
    float p[8][2];
    #pragma unroll
    for (int i = 8; i <= 15; ++i) {
        const float2* ri = (const float2*)(ws + ((1u << (i + 2)) - 4)
                                              + (B & ((2u << i) - 1)) * 2);
        float2 v = *ri;
        p[i - 8][0] = v.x;
        p[i - 8][1] = v.y;
    }
    #pragma unroll
    for (int i = 0; i < 8; ++i) {
        const float* cf = outLf + (i + 8) * 64;
        const float q0 = p[i][0], q1 = p[i][1];
        #pragma unroll
        for (int o = 0; o < 32; ++o)
            acc[o] += q0 * cf[o * 2] + q1 * cf[o * 2 + 1];
    }
    {
        const unsigned Blo = B & 0xFFFFu;
        const float* r16 = ws + ((1u << 18) - 4);
        const float2* rA = (const float2*)(r16 + Blo * 2);
        const float2* rC = (const float2*)(r16 + (Blo + 65536u) * 2);
        float2 vA = *rA, vC = *rC;
        float A0 = vA.x, A1 = vA.y;
        float c0 = vC.x, c1 = vC.y;
        {
            const int pick = (B >> 16) & 1;
            const float q0 = pick ? c0 : A0, q1 = pick ? c1 : A1;
            const float* cf = outLf + 16 * 64;
            #pragma unroll
            for (int o = 0; o < 32; ++o)
                acc[o] += q0 * cf[o * 2] + q1 * cf[o * 2 + 1];
        }
        #pragma unroll
        for (int l = 17; l <= 20; ++l) {
            const int s = (B >> (l - 1)) & 1;
            const float* WL = tLf + (l - 1) * 4;
            const float* WR = tRf + (l - 1) * 4;
            const float* bL = tLbf + (l - 1) * 2;
            const float* bR = tRbf + (l - 1) * 2;
            const float w00 = s ? WR[0] : WL[0], w01 = s ? WR[1] : WL[1];
            const float w10 = s ? WR[2] : WL[2], w11 = s ? WR[3] : WL[3];
            const float b0  = s ? bR[0] : bL[0], b1  = s ? bR[1] : bL[1];
            const float nA0 = w00 * A0 + w01 * A1 + b0;
            const float nA1 = w10 * A0 + w11 * A1 + b1;
            const float nc0 = w00 * c0 + w01 * c1 + b0;
            const float nc1 = w10 * c0 + w11 * c1 + b1;
            A0 = nA0; A1 = nA1; c0 = nc0; c1 = nc1;
            const int pick = (B >> l) & 1;
            const float q0 = pick ? c0 : A0, q1 = pick ? c1 : A1;
            const float* cf = outLf + l * 64;
            #pragma unroll
            for (int o = 0; o < 32; ++o)
                acc[o] += q0 * cf[o * 2] + q1 * cf[o * 2 + 1];
        }
    }
    #pragma unroll
    for (int q = 0; q < 8; ++q) {
        st[tid * 8 + (q ^ (tid & 7))] =
            (floatx4){acc[q * 4 + 0], acc[q * 4 + 1],
                      acc[q * 4 + 2], acc[q * 4 + 3]};
    }
    __syncthreads();
    {
        const int w = tid >> 6, lane = tid & 63;
        const int x = (lane & 7) ^ (lane >> 3);
        floatx4* dst = (floatx4*)(out + (size_t)blockIdx.x * 8192u
                                      + (unsigned)w * 2048u + (unsigned)lane * 4u);
        #pragma unroll
        for (int j = 0; j < 8; ++j) {
            const int m = w * 64 + j * 8 + (lane >> 3);
            __builtin_nontemporal_store(st[m * 8 + x], dst + j * 64);
        }
    }
}

extern "C" void kernel_launch(void* const* d_in, const int* in_sizes, int n_in,
                              void* d_out, int out_size, void* d_ws, size_t ws_size,
                              hipStream_t stream) {
    const float* x     = (const float*)d_in[0];
    const float* inL   = (const float*)d_in[1];
    const float* inR   = (const float*)d_in[2];
    const float* inLb  = (const float*)d_in[3];
    const float* inRb  = (const float*)d_in[4];
    const float* treeL = (const float*)d_in[5];
    const float* treeR = (const float*)d_in[6];
    const float* treeLb= (const float*)d_in[7];
    const float* treeRb= (const float*)d_in[8];
    const float* outL0 = (const float*)d_in[9];
    const float* outLs = (const float*)d_in[10];
    const float* outB  = (const float*)d_in[11];
    float* ws = (float*)d_ws;
    float* out = (float*)d_out;

    // C14 fold path needs ws up to byte offset (C14OFF + 2^20 floats)*4 = 8 MB
    const bool use_fold = ws_size >= ((size_t)C14OFF + (1u << 20)) * sizeof(float);

    hipLaunchKernelGGL(k_prefix, dim3(1), dim3(1024), 0, stream,
                       x, inL, inR, inLb, inRb, treeL, treeR, treeLb, treeRb,
                       outL0, outLs, outB, ws);
    hipLaunchKernelGGL(k_mid, dim3(112), dim3(256), 0, stream, ws);
    if (use_fold) {
        hipLaunchKernelGGL(k_c14, dim3(128), dim3(256), 0, stream, ws);
        hipLaunchKernelGGL(k_final_fold, dim3(1u << 13), dim3(256), 0, stream, ws, out);
    } else {
        hipLaunchKernelGGL(k_final_legacy, dim3(1u << 13), dim3(256), 0, stream, ws, out);
    }
}

// Round 4
// 360.411 us; speedup vs baseline: 2.1219x; 1.0535x over previous
//
#include <hip/hip_runtime.h>
#include <hip/hip_bf16.h>

// BinTreeNetwork (ALL TENSORS FP32):
//   out[B, o] = out0[o] + out_bias[o]
//             + sum_{i=0}^{20} res_i[B mod 2^{i+1}, :] . out_layers[i][o, :]
// res tables (2^{i+1} rows x 2 cols, fp32) for levels 0..16 in ws;
// levels 17..20 computed on the fly in k_final via two register chains
// from the two level-16 ancestor rows (b<<16)|(B&0xFFFF).
//   res_j[m,k'] = sum_k res_{j-1}[src,k] * W_s(layer j-1)[k',k] + b_s[k']
//   src = ((m>>j)<<(j-1)) | (m & (2^{j-1}-1)),  s = (m>>(j-1))&1  (drop 2nd-MSB)
//
// ws layout (fp32 elements):
//   [0, 2^19-4)  res tables, level i at (1<<(i+2))-4
//   P0 = 1<<19:
//     +0      base[32]     = out0.x + out_bias
//     +32     outLf[21*64] = out_layers copy
//     +1376   tLf[84], +1460 tRf[84], +1544 tLbf[42], +1586 tRbf[42]
//     +1664   dots[36]     (k_dots -> k_levels scratch)
//     +2048   C7[256*32]   = base + levels 0..7 pre-folded
//   C14OFF = 1<<20 floats (4 MB): C14[2^15][32]   (fallback path, ws >= 8 MB)
//   C16OFF = 1<<21 floats (8 MB): C16[2^17][32]   (main path, ws >= 24 MB)
//            C16 = C7 + levels 8..16 pre-folded; k_final = C16 + chains 17..20

#define P0 (1u << 19)
#define C14OFF (1u << 20)
#define C16OFF (1u << 21)

typedef float floatx4 __attribute__((ext_vector_type(4)));

// ---------------- K0: 36 dot products row.x, one block each -----------------
__global__ __launch_bounds__(1024) void k_dots(
    const float* __restrict__ x,
    const float* __restrict__ inL,
    const float* __restrict__ inR,
    const float* __restrict__ outL0,
    float* __restrict__ ws)
{
    __shared__ float red[16];
    const int d = blockIdx.x;
    const int tid = threadIdx.x;
    const float* row =
        (d < 2) ? inL + d * 4096 :
        (d < 4) ? inR + (d - 2) * 4096 :
                  outL0 + (d - 4) * 4096;
    floatx4 a = ((const floatx4*)row)[tid];
    floatx4 b = ((const floatx4*)x)[tid];
    float s = a.x * b.x + a.y * b.y + a.z * b.z + a.w * b.w;
    #pragma unroll
    for (int off = 32; off; off >>= 1) s += __shfl_down(s, off, 64);
    if ((tid & 63) == 0) red[tid >> 6] = s;
    __syncthreads();
    if (tid < 16) {
        float v = red[tid];
        #pragma unroll
        for (int off = 8; off; off >>= 1) v += __shfl_down(v, off, 16);
        if (tid == 0) ws[P0 + 1664 + d] = v;
    }
}

// ---------------- K1: seed + levels 1..13 + param copy + C7 (1 block) --------
__global__ __launch_bounds__(1024) void k_levels(
    const float* __restrict__ inLb,
    const float* __restrict__ inRb,
    const float* __restrict__ treeL,
    const float* __restrict__ treeR,
    const float* __restrict__ treeLb,
    const float* __restrict__ treeRb,
    const float* __restrict__ outLs,
    const float* __restrict__ outB,
    float* __restrict__ ws)
{
    const int tid = threadIdx.x;
    float* base  = ws + P0;
    float* outLf = ws + P0 + 32;
    float* tLf   = ws + P0 + 1376;
    float* tRf   = ws + P0 + 1460;
    float* tLbf  = ws + P0 + 1544;
    float* tRbf  = ws + P0 + 1586;
    const float* dots = ws + P0 + 1664;
    float* C7    = ws + P0 + 2048;

    for (int i = tid; i < 21 * 64; i += 1024) outLf[i] = outLs[i];
    if (tid < 84)                      tLf[tid]        = treeL[tid];
    else if (tid < 168)                tRf[tid - 84]   = treeR[tid - 84];
    else if (tid < 210)                tLbf[tid - 168] = treeLb[tid - 168];
    else if (tid < 252)                tRbf[tid - 210] = treeRb[tid - 210];
    if (tid < 32) base[tid] = dots[4 + tid] + outB[tid];
    if (tid < 2) {
        // res_0 row j = {left0[j], right0[j]}
        ws[tid * 2 + 0] = dots[tid]     + inLb[tid];
        ws[tid * 2 + 1] = dots[2 + tid] + inRb[tid];
    }
    __syncthreads();

    // levels 1..13
    for (int i = 1; i <= 13; ++i) {
        const float* prev = ws + ((1u << (i + 1)) - 4);
        float* cur        = ws + ((1u << (i + 2)) - 4);
        const int rows = 1 << (i + 1);
        const int lowmask = (1 << (i - 1)) - 1;
        for (int m = tid; m < rows; m += 1024) {
            const int src = ((m >> i) << (i - 1)) | (m & lowmask);
            const int s = (m >> (i - 1)) & 1;
            const float* W  = (s ? tRf  : tLf)  + (i - 1) * 4;
            const float* bb = (s ? tRbf : tLbf) + (i - 1) * 2;
            const float p0 = prev[src * 2], p1 = prev[src * 2 + 1];
            cur[m * 2 + 0] = W[0] * p0 + W[1] * p1 + bb[0];
            cur[m * 2 + 1] = W[2] * p0 + W[3] * p1 + bb[1];
        }
        __syncthreads();
    }

    // C7[m][o] = base[o] + sum_{i=0}^{7} res_i[m mod 2^{i+1}] . outL[i][o]
    for (int idx = tid; idx < 8192; idx += 1024) {
        const int m = idx >> 5, o = idx & 31;
        float s = base[o];
        #pragma unroll
        for (int i = 0; i < 8; ++i) {
            const float* ri = ws + ((1u << (i + 2)) - 4) + (m & ((2 << i) - 1)) * 2;
            s += ri[0] * outLf[i * 64 + o * 2] + ri[1] * outLf[i * 64 + o * 2 + 1];
        }
        C7[idx] = s;
    }
}

// ---------------- K2: levels 14..16 via per-block register chains from res_13 -
__global__ __launch_bounds__(256) void k_mid(float* __restrict__ ws)
{
    const int blk = blockIdx.x;
    int j, b;
    if      (blk < 16) { j = 14; b = blk; }
    else if (blk < 48) { j = 15; b = blk - 16; }
    else               { j = 16; b = blk - 48; }

    const float* tLf  = ws + P0 + 1376;
    const float* tRf  = ws + P0 + 1460;
    const float* tLbf = ws + P0 + 1544;
    const float* tRbf = ws + P0 + 1586;

    // walk base row from level j down to 13, recording per-level select bits
    unsigned m = (unsigned)b << 11;
    const unsigned basej = m;
    unsigned sbits = 0;
    for (int l = j; l > 13; --l) {
        sbits |= ((m >> (l - 1)) & 1u) << l;
        m = ((m >> l) << (l - 1)) | (m & ((1u << (l - 1)) - 1));
    }

    // this thread's 8 rows of res_13 (aligned float4 x4)
    const int r0 = threadIdx.x * 8;
    const floatx4* s4 = (const floatx4*)(ws + ((1u << 15) - 4) + (m + r0) * 2);
    floatx4 a0 = s4[0], a1 = s4[1], a2 = s4[2], a3 = s4[3];
    float r[8][2] = {{a0.x,a0.y},{a0.z,a0.w},{a1.x,a1.y},{a1.z,a1.w},
                     {a2.x,a2.y},{a2.z,a2.w},{a3.x,a3.y},{a3.z,a3.w}};

    for (int l = 14; l <= j; ++l) {
        const int s = (sbits >> l) & 1;
        const float* W  = (s ? tRf  : tLf)  + (l - 1) * 4;
        const float* bb = (s ? tRbf : tLbf) + (l - 1) * 2;
        const float w00 = W[0], w01 = W[1], w10 = W[2], w11 = W[3];
        const float b0 = bb[0], b1 = bb[1];
        #pragma unroll
        for (int q = 0; q < 8; ++q) {
            const float p0 = r[q][0], p1 = r[q][1];
            r[q][0] = w00 * p0 + w01 * p1 + b0;
            r[q][1] = w10 * p0 + w11 * p1 + b1;
        }
    }

    floatx4* d4 = (floatx4*)(ws + ((1u << (j + 2)) - 4) + (basej + r0) * 2);
    d4[0] = (floatx4){r[0][0], r[0][1], r[1][0], r[1][1]};
    d4[1] = (floatx4){r[2][0], r[2][1], r[3][0], r[3][1]};
    d4[2] = (floatx4){r[4][0], r[4][1], r[5][0], r[5][1]};
    d4[3] = (floatx4){r[6][0], r[6][1], r[7][0], r[7][1]};
}

// ---------------- K2b: fold levels 8..16 into C16[2^17][32] ------------------
// C16[m] = C7[m&255] + sum_{i=8..16} res_i[m mod 2^{i+1}] . outL[i]
// 16 MB, built once (~3 us); regular stores (L2-allocating, full-line wb).
__global__ __launch_bounds__(256) void k_c16(float* __restrict__ ws)
{
    const unsigned m = blockIdx.x * 256u + threadIdx.x;   // 2^17 threads
    const float* outLf = ws + P0 + 32;
    const float* C7    = ws + P0 + 2048;

    float acc[32];
    const floatx4* c4 = (const floatx4*)(C7 + (m & 255u) * 32);
    #pragma unroll
    for (int q = 0; q < 8; ++q) {
        floatx4 v = c4[q];
        acc[q * 4 + 0] = v.x; acc[q * 4 + 1] = v.y;
        acc[q * 4 + 2] = v.z; acc[q * 4 + 3] = v.w;
    }
    #pragma unroll
    for (int i = 8; i <= 16; ++i) {
        const float2 v = *(const float2*)(ws + ((1u << (i + 2)) - 4)
                                             + (m & ((2u << i) - 1)) * 2);
        const float* cf = outLf + i * 64;
        #pragma unroll
        for (int o = 0; o < 32; ++o)
            acc[o] += v.x * cf[o * 2] + v.y * cf[o * 2 + 1];
    }
    floatx4* dst = (floatx4*)(ws + C16OFF + (size_t)m * 32);
    #pragma unroll
    for (int q = 0; q < 8; ++q)
        dst[q] = (floatx4){acc[q * 4 + 0], acc[q * 4 + 1],
                           acc[q * 4 + 2], acc[q * 4 + 3]};
}

// ---------------- K2b (fallback): fold levels 8..14 into C14[2^15][32] -------
__global__ __launch_bounds__(256) void k_c14(float* __restrict__ ws)
{
    const unsigned m = blockIdx.x * 256u + threadIdx.x;   // 2^15 threads
    const float* outLf = ws + P0 + 32;
    const float* C7    = ws + P0 + 2048;

    float acc[32];
    const floatx4* c4 = (const floatx4*)(C7 + (m & 255u) * 32);
    #pragma unroll
    for (int q = 0; q < 8; ++q) {
        floatx4 v = c4[q];
        acc[q * 4 + 0] = v.x; acc[q * 4 + 1] = v.y;
        acc[q * 4 + 2] = v.z; acc[q * 4 + 3] = v.w;
    }
    #pragma unroll
    for (int i = 8; i <= 14; ++i) {
        const float2 v = *(const float2*)(ws + ((1u << (i + 2)) - 4)
                                             + (m & ((2u << i) - 1)) * 2);
        const float* cf = outLf + i * 64;
        #pragma unroll
        for (int o = 0; o < 32; ++o)
            acc[o] += v.x * cf[o * 2] + v.y * cf[o * 2 + 1];
    }
    floatx4* dst = (floatx4*)(ws + C14OFF + m * 32);
    #pragma unroll
    for (int q = 0; q < 8; ++q)
        dst[q] = (floatx4){acc[q * 4 + 0], acc[q * 4 + 1],
                           acc[q * 4 + 2], acc[q * 4 + 3]};
}

// ---------------- K3: final gather-sum (C16 path) ----------------------------
// Per leaf: C16 row + register chains 17..20 (~290 FMA/leaf).
// Store path: LDS transpose (XOR-swizzled, conflict-free) -> contiguous
// 1 KiB-per-instruction nontemporal stores, 1.0x write amplification.
__global__ __launch_bounds__(256) void k_final_c16(const float* __restrict__ ws,
                                                   float* __restrict__ out)
{
    __shared__ floatx4 st[256 * 8];   // 32 KiB
    const int tid = threadIdx.x;
    const unsigned B = blockIdx.x * 256u + tid;
    const float* outLf = ws + P0 + 32;
    const float* tLf   = ws + P0 + 1376;
    const float* tRf   = ws + P0 + 1460;
    const float* tLbf  = ws + P0 + 1544;
    const float* tRbf  = ws + P0 + 1586;
    const float* C16   = ws + C16OFF;

    float acc[32];
    {   // C16 row (contiguous 128 B, 16B-aligned)
        const floatx4* c4 = (const floatx4*)(C16 + (size_t)(B & 0x1FFFFu) * 32);
        #pragma unroll
        for (int q = 0; q < 8; ++q) {
            floatx4 v = c4[q];
            acc[q * 4 + 0] = v.x; acc[q * 4 + 1] = v.y;
            acc[q * 4 + 2] = v.z; acc[q * 4 + 3] = v.w;
        }
    }

    // levels 17..20: two register chains from the two level-16 ancestor rows
    // (level-16 contribution itself is folded into C16)
    {
        const unsigned Blo = B & 0xFFFFu;
        const float* r16 = ws + ((1u << 18) - 4);
        float2 vA = *(const float2*)(r16 + Blo * 2);
        float2 vC = *(const float2*)(r16 + (Blo + 65536u) * 2);
        float A0 = vA.x, A1 = vA.y;   // MSB=0 chain
        float c0 = vC.x, c1 = vC.y;   // MSB=1 chain
        #pragma unroll
        for (int l = 17; l <= 20; ++l) {
            const int s = (B >> (l - 1)) & 1;
            const float* WL = tLf + (l - 1) * 4;   // uniform -> scalar loads
            const float* WR = tRf + (l - 1) * 4;
            const float* bL = tLbf + (l - 1) * 2;
            const float* bR = tRbf + (l - 1) * 2;
            const float w00 = s ? WR[0] : WL[0], w01 = s ? WR[1] : WL[1];
            const float w10 = s ? WR[2] : WL[2], w11 = s ? WR[3] : WL[3];
            const float b0  = s ? bR[0] : bL[0], b1  = s ? bR[1] : bL[1];
            const float nA0 = w00 * A0 + w01 * A1 + b0;
            const float nA1 = w10 * A0 + w11 * A1 + b1;
            const float nc0 = w00 * c0 + w01 * c1 + b0;
            const float nc1 = w10 * c0 + w11 * c1 + b1;
            A0 = nA0; A1 = nA1; c0 = nc0; c1 = nc1;
            const int pick = (B >> l) & 1;
            const float q0 = pick ? c0 : A0, q1 = pick ? c1 : A1;
            const float* cf = outLf + l * 64;
            #pragma unroll
            for (int o = 0; o < 32; ++o)
                acc[o] += q0 * cf[o * 2] + q1 * cf[o * 2 + 1];
        }
    }

    // ---- transpose through LDS, then fully-coalesced 1 KiB/instr nt stores --
    #pragma unroll
    for (int q = 0; q < 8; ++q) {
        st[tid * 8 + (q ^ (tid & 7))] =
            (floatx4){acc[q * 4 + 0], acc[q * 4 + 1],
                      acc[q * 4 + 2], acc[q * 4 + 3]};
    }
    __syncthreads();
    {
        const int w = tid >> 6, lane = tid & 63;
        const int x = (lane & 7) ^ (lane >> 3);
        floatx4* dst = (floatx4*)(out + (size_t)blockIdx.x * 8192u
                                      + (unsigned)w * 2048u + (unsigned)lane * 4u);
        #pragma unroll
        for (int j = 0; j < 8; ++j) {
            const int m = w * 64 + j * 8 + (lane >> 3);
            __builtin_nontemporal_store(st[m * 8 + x], dst + j * 64);
        }
    }
}

// ---------------- K3 (fallback, C14 path): verified round-2 kernel -----------
__global__ __launch_bounds__(256) void k_final_fold(const float* __restrict__ ws,
                                                    float* __restrict__ out)
{
    __shared__ floatx4 st[256 * 8];
    const int tid = threadIdx.x;
    const unsigned B = blockIdx.x * 256u + tid;
    const float* outLf = ws + P0 + 32;
    const float* tLf   = ws + P0 + 1376;
    const float* tRf   = ws + P0 + 1460;
    const float* tLbf  = ws + P0 + 1544;
    const float* tRbf  = ws + P0 + 1586;
    const float* C14   = ws + C14OFF;

    float acc[32];
    {
        const floatx4* c4 = (const floatx4*)(C14 + (B & 0x7FFFu) * 32);
        #pragma unroll
        for (int q = 0; q < 8; ++q) {
            floatx4 v = c4[q];
            acc[q * 4 + 0] = v.x; acc[q * 4 + 1] = v.y;
            acc[q * 4 + 2] = v.z; acc[q * 4 + 3] = v.w;
        }
    }
    {
        const float2 v = *(const float2*)(ws + ((1u << 17) - 4)
                                             + (B & 0xFFFFu) * 2);
        const float* cf = outLf + 15 * 64;
        #pragma unroll
        for (int o = 0; o < 32; ++o)
            acc[o] += v.x * cf[o * 2] + v.y * cf[o * 2 + 1];
    }
    {
        const unsigned Blo = B & 0xFFFFu;
        const float* r16 = ws + ((1u << 18) - 4);
        float2 vA = *(const float2*)(r16 + Blo * 2);
        float2 vC = *(const float2*)(r16 + (Blo + 65536u) * 2);
        float A0 = vA.x, A1 = vA.y;
        float c0 = vC.x, c1 = vC.y;
        {
            const int pick = (B >> 16) & 1;
            const float q0 = pick ? c0 : A0, q1 = pick ? c1 : A1;
            const float* cf = outLf + 16 * 64;
            #pragma unroll
            for (int o = 0; o < 32; ++o)
                acc[o] += q0 * cf[o * 2] + q1 * cf[o * 2 + 1];
        }
        #pragma unroll
        for (int l = 17; l <= 20; ++l) {
            const int s = (B >> (l - 1)) & 1;
            const float* WL = tLf + (l - 1) * 4;
            const float* WR = tRf + (l - 1) * 4;
            const float* bL = tLbf + (l - 1) * 2;
            const float* bR = tRbf + (l - 1) * 2;
            const float w00 = s ? WR[0] : WL[0], w01 = s ? WR[1] : WL[1];
            const float w10 = s ? WR[2] : WL[2], w11 = s ? WR[3] : WL[3];
            const float b0  = s ? bR[0] : bL[0], b1  = s ? bR[1] : bL[1];
            const float nA0 = w00 * A0 + w01 * A1 + b0;
            const float nA1 = w10 * A0 + w11 * A1 + b1;
            const float nc0 = w00 * c0 + w01 * c1 + b0;
            const float nc1 = w10 * c0 + w11 * c1 + b1;
            A0 = nA0; A1 = nA1; c0 = nc0; c1 = nc1;
            const int pick = (B >> l) & 1;
            const float q0 = pick ? c0 : A0, q1 = pick ? c1 : A1;
            const float* cf = outLf + l * 64;
            #pragma unroll
            for (int o = 0; o < 32; ++o)
                acc[o] += q0 * cf[o * 2] + q1 * cf[o * 2 + 1];
        }
    }
    #pragma unroll
    for (int q = 0; q < 8; ++q) {
        st[tid * 8 + (q ^ (tid & 7))] =
            (floatx4){acc[q * 4 + 0], acc[q * 4 + 1],
                      acc[q * 4 + 2], acc[q * 4 + 3]};
    }
    __syncthreads();
    {
        const int w = tid >> 6, lane = tid & 63;
        const int x = (lane & 7) ^ (lane >> 3);
        floatx4* dst = (floatx4*)(out + (size_t)blockIdx.x * 8192u
                                      + (unsigned)w * 2048u + (unsigned)lane * 4u);
        #pragma unroll
        for (int j = 0; j < 8; ++j) {
            const int m = w * 64 + j * 8 + (lane >> 3);
            __builtin_nontemporal_store(st[m * 8 + x], dst + j * 64);
        }
    }
}

// ---------------- K3 (fallback, small ws): verified round-1 kernel -----------
__global__ __launch_bounds__(256) void k_final_legacy(const float* __restrict__ ws,
                                                      float* __restrict__ out)
{
    __shared__ floatx4 st[256 * 8];
    const int tid = threadIdx.x;
    const unsigned B = blockIdx.x * 256u + tid;
    const float* outLf = ws + P0 + 32;
    const float* tLf   = ws + P0 + 1376;
    const float* tRf   = ws + P0 + 1460;
    const float* tLbf  = ws + P0 + 1544;
    const float* tRbf  = ws + P0 + 1586;
    const float* C7    = ws + P0 + 2048;

    float acc[32];
    {
        const floatx4* c4 = (const floatx4*)(C7 + (B & 255u) * 32);
        #pragma unroll
        for (int q = 0; q < 8; ++q) {
            floatx4 v = c4[q];
            acc[q * 4 + 0] = v.x; acc[q * 4 + 1] = v.y;
            acc[q * 4 + 2] = v.z; acc[q * 4 + 3] = v.w;
        }
    }
    float p[8][2];
    #pragma unroll
    for (int i = 8; i <= 15; ++i) {
        const float2* ri = (const float2*)(ws + ((1u << (i + 2)) - 4)
                                              + (B & ((2u << i) - 1)) * 2);
        float2 v = *ri;
        p[i - 8][0] = v.x;
        p[i - 8][1] = v.y;
    }
    #pragma unroll
    for (int i = 0; i < 8; ++i) {
        const float* cf = outLf + (i + 8) * 64;
        const float q0 = p[i][0], q1 = p[i][1];
        #pragma unroll
        for (int o = 0; o < 32; ++o)
            acc[o] += q0 * cf[o * 2] + q1 * cf[o * 2 + 1];
    }
    {
        const unsigned Blo = B & 0xFFFFu;
        const float* r16 = ws + ((1u << 18) - 4);
        float2 vA = *(const float2*)(r16 + Blo * 2);
        float2 vC = *(const float2*)(r16 + (Blo + 65536u) * 2);
        float A0 = vA.x, A1 = vA.y;
        float c0 = vC.x, c1 = vC.y;
        {
            const int pick = (B >> 16) & 1;
            const float q0 = pick ? c0 : A0, q1 = pick ? c1 : A1;
            const float* cf = outLf + 16 * 64;
            #pragma unroll
            for (int o = 0; o < 32; ++o)
                acc[o] += q0 * cf[o * 2] + q1 * cf[o * 2 + 1];
        }
        #pragma unroll
        for (int l = 17; l <= 20; ++l) {
            const int s = (B >> (l - 1)) & 1;
            const float* WL = tLf + (l - 1) * 4;
            const float* WR = tRf + (l - 1) * 4;
            const float* bL = tLbf + (l - 1) * 2;
            const float* bR = tRbf + (l - 1) * 2;
            const float w00 = s ? WR[0] : WL[0], w01 = s ? WR[1] : WL[1];
            const float w10 = s ? WR[2] : WL[2], w11 = s ? WR[3] : WL[3];
            const float b0  = s ? bR[0] : bL[0], b1  = s ? bR[1] : bL[1];
            const float nA0 = w00 * A0 + w01 * A1 + b0;
            const float nA1 = w10 * A0 + w11 * A1 + b1;
            const float nc0 = w00 * c0 + w01 * c1 + b0;
            const float nc1 = w10 * c0 + w11 * c1 + b1;
            A0 = nA0; A1 = nA1; c0 = nc0; c1 = nc1;
            const int pick = (B >> l) & 1;
            const float q0 = pick ? c0 : A0, q1 = pick ? c1 : A1;
            const float* cf = outLf + l * 64;
            #pragma unroll
            for (int o = 0; o < 32; ++o)
                acc[o] += q0 * cf[o * 2] + q1 * cf[o * 2 + 1];
        }
    }
    #pragma unroll
    for (int q = 0; q < 8; ++q) {
        st[tid * 8 + (q ^ (tid & 7))] =
            (floatx4){acc[q * 4 + 0], acc[q * 4 + 1],
                      acc[q * 4 + 2], acc[q * 4 + 3]};
    }
    __syncthreads();
    {
        const int w = tid >> 6, lane = tid & 63;
        const int x = (lane & 7) ^ (lane >> 3);
        floatx4* dst = (floatx4*)(out + (size_t)blockIdx.x * 8192u
                                      + (unsigned)w * 2048u + (unsigned)lane * 4u);
        #pragma unroll
        for (int j = 0; j < 8; ++j) {
            const int m = w * 64 + j * 8 + (lane >> 3);
            __builtin_nontemporal_store(st[m * 8 + x], dst + j * 64);
        }
    }
}

extern "C" void kernel_launch(void* const* d_in, const int* in_sizes, int n_in,
                              void* d_out, int out_size, void* d_ws, size_t ws_size,
                              hipStream_t stream) {
    const float* x     = (const float*)d_in[0];
    const float* inL   = (const float*)d_in[1];
    const float* inR   = (const float*)d_in[2];
    const float* inLb  = (const float*)d_in[3];
    const float* inRb  = (const float*)d_in[4];
    const float* treeL = (const float*)d_in[5];
    const float* treeR = (const float*)d_in[6];
    const float* treeLb= (const float*)d_in[7];
    const float* treeRb= (const float*)d_in[8];
    const float* outL0 = (const float*)d_in[9];
    const float* outLs = (const float*)d_in[10];
    const float* outB  = (const float*)d_in[11];
    float* ws = (float*)d_ws;
    float* out = (float*)d_out;

    const bool use_c16 = ws_size >= ((size_t)C16OFF + (1u << 22)) * sizeof(float); // 24 MB
    const bool use_c14 = ws_size >= ((size_t)C14OFF + (1u << 20)) * sizeof(float); //  8 MB

    hipLaunchKernelGGL(k_dots, dim3(36), dim3(1024), 0, stream,
                       x, inL, inR, outL0, ws);
    hipLaunchKernelGGL(k_levels, dim3(1), dim3(1024), 0, stream,
                       inLb, inRb, treeL, treeR, treeLb, treeRb, outLs, outB, ws);
    hipLaunchKernelGGL(k_mid, dim3(112), dim3(256), 0, stream, ws);
    if (use_c16) {
        hipLaunchKernelGGL(k_c16, dim3(512), dim3(256), 0, stream, ws);
        hipLaunchKernelGGL(k_final_c16, dim3(1u << 13), dim3(256), 0, stream, ws, out);
    } else if (use_c14) {
        hipLaunchKernelGGL(k_c14, dim3(128), dim3(256), 0, stream, ws);
        hipLaunchKernelGGL(k_final_fold, dim3(1u << 13), dim3(256), 0, stream, ws, out);
    } else {
        hipLaunchKernelGGL(k_final_legacy, dim3(1u << 13), dim3(256), 0, stream, ws, out);
    }
}

// Round 5
// 334.728 us; speedup vs baseline: 2.2847x; 1.0767x over previous
//
#include <hip/hip_runtime.h>
#include <hip/hip_bf16.h>

// BinTreeNetwork (ALL TENSORS FP32):
//   out[B, o] = out0[o] + out_bias[o]
//             + sum_{i=0}^{20} res_i[B mod 2^{i+1}, :] . out_layers[i][o, :]
//
// Main path (ws >= 24 MB):
//   k_dots:  36 dot products (x . rows of inL/inR/outL0) -> ws dots[36]
//   k_paths: ALL res-table rows, levels 0..16, fully parallel. Row (i,m) is
//            a chain of i affine 2x2 maps from seed res_0[r]:
//              descend: s_l=(m>>(l-1))&1; m=((m>>l)<<(l-1))|(m&(2^{l-1}-1))
//              ascend:  v = W_{s_l}(layer l-1) v + b_{s_l}
//            Level i row m sits at float offset 2t+4 (u=2^{i+1}+m, t=u-4):
//            one contiguous coalesced float2 store per thread.
//   k_c16f:  C16[m][o] = (dots[4+o]+outB[o]) + sum_{i=0..16} res_i[m mod 2^{i+1}].outL[i][o]
//            (2^17 x 32 fp32 = 16 MB at C16OFF)
//   k_final_c16: out[B] = C16[B&0x1FFFF] + chains 17..20 from the two
//            level-16 ancestor rows; LDS-transposed 1 KiB/instr nt stores.
//
// ws layout (fp32 elements):
//   [0, 2^19-4)  res tables, level i at (1<<(i+2))-4
//   P0 = 1<<19: +1664 dots[36]
//     (legacy fallback also uses: +0 base, +32 outLf, +1376 tLf, +1460 tRf,
//      +1544 tLbf, +1586 tRbf, +2048 C7)
//   C14OFF = 1<<20 floats: C14 (fallback, ws >= 8 MB)
//   C16OFF = 1<<21 floats: C16 (main, ws >= 24 MB)

#define P0 (1u << 19)
#define C14OFF (1u << 20)
#define C16OFF (1u << 21)

typedef float floatx4 __attribute__((ext_vector_type(4)));

// ---------------- K0: 36 dot products row.x, one block each -----------------
__global__ __launch_bounds__(1024) void k_dots(
    const float* __restrict__ x,
    const float* __restrict__ inL,
    const float* __restrict__ inR,
    const float* __restrict__ outL0,
    float* __restrict__ ws)
{
    __shared__ float red[16];
    const int d = blockIdx.x;
    const int tid = threadIdx.x;
    const float* row =
        (d < 2) ? inL + d * 4096 :
        (d < 4) ? inR + (d - 2) * 4096 :
                  outL0 + (d - 4) * 4096;
    floatx4 a = ((const floatx4*)row)[tid];
    floatx4 b = ((const floatx4*)x)[tid];
    float s = a.x * b.x + a.y * b.y + a.z * b.z + a.w * b.w;
    #pragma unroll
    for (int off = 32; off; off >>= 1) s += __shfl_down(s, off, 64);
    if ((tid & 63) == 0) red[tid >> 6] = s;
    __syncthreads();
    if (tid < 16) {
        float v = red[tid];
        #pragma unroll
        for (int off = 8; off; off >>= 1) v += __shfl_down(v, off, 16);
        if (tid == 0) ws[P0 + 1664 + d] = v;
    }
}

// ---------------- K1 (main): all res-table rows in parallel ------------------
__global__ __launch_bounds__(256) void k_paths(
    const float* __restrict__ treeL,
    const float* __restrict__ treeR,
    const float* __restrict__ treeLb,
    const float* __restrict__ treeRb,
    const float* __restrict__ inLb,
    const float* __restrict__ inRb,
    float* __restrict__ ws)
{
    const unsigned t = blockIdx.x * 256u + threadIdx.x;
    const float* dots = ws + P0 + 1664;

    if (t < 2) {   // level-0 seed rows
        ws[t * 2 + 0] = dots[t]     + inLb[t];
        ws[t * 2 + 1] = dots[2 + t] + inRb[t];
    }
    if (t >= (1u << 18) - 4) return;

    const unsigned u = t + 4u;
    const int i = (31 - __clz(u)) - 1;          // level, in [1,16]
    unsigned m = u - (1u << (i + 1));           // row within level i
    unsigned sbits = 0;
    for (int l = i; l >= 1; --l) {              // descend, record selects
        sbits |= ((m >> (l - 1)) & 1u) << l;
        m = ((m >> l) << (l - 1)) | (m & ((1u << (l - 1)) - 1u));
    }
    // m in {0,1}: seed
    float v0 = dots[m]     + inLb[m];
    float v1 = dots[2 + m] + inRb[m];
    for (int l = 1; l <= i; ++l) {              // ascend, apply affine chain
        const int s = (sbits >> l) & 1;
        const float* W  = (s ? treeR  : treeL)  + (l - 1) * 4;
        const float* bb = (s ? treeRb : treeLb) + (l - 1) * 2;
        const float n0 = W[0] * v0 + W[1] * v1 + bb[0];
        const float n1 = W[2] * v0 + W[3] * v1 + bb[1];
        v0 = n0; v1 = n1;
    }
    // level i row m lives at float offset (1<<(i+2))-4 + 2m == 2t+4
    ws[2 * t + 4] = v0;
    ws[2 * t + 5] = v1;
}

// ---------------- K2 (main): fold base + levels 0..16 into C16[2^17][32] ----
__global__ __launch_bounds__(256) void k_c16f(
    const float* __restrict__ outLs,
    const float* __restrict__ outB,
    float* __restrict__ ws)
{
    const unsigned m = blockIdx.x * 256u + threadIdx.x;   // 2^17 threads
    const float* dots = ws + P0 + 1664;

    float acc[32];
    #pragma unroll
    for (int o = 0; o < 32; ++o) acc[o] = dots[4 + o] + outB[o];
    #pragma unroll
    for (int i = 0; i <= 16; ++i) {
        const float2 v = *(const float2*)(ws + ((1u << (i + 2)) - 4)
                                             + (m & ((2u << i) - 1)) * 2);
        const float* cf = outLs + i * 64;
        #pragma unroll
        for (int o = 0; o < 32; ++o)
            acc[o] += v.x * cf[o * 2] + v.y * cf[o * 2 + 1];
    }
    floatx4* dst = (floatx4*)(ws + C16OFF + (size_t)m * 32);
    #pragma unroll
    for (int q = 0; q < 8; ++q)
        dst[q] = (floatx4){acc[q * 4 + 0], acc[q * 4 + 1],
                           acc[q * 4 + 2], acc[q * 4 + 3]};
}

// ---------------- K3 (main): final gather-sum --------------------------------
// Per leaf: C16 row + register chains 17..20 (~290 FMA/leaf).
// Store path: LDS transpose (XOR-swizzled, conflict-free) -> contiguous
// 1 KiB-per-instruction nontemporal stores, 1.0x write amplification.
__global__ __launch_bounds__(256) void k_final_c16(
    const float* __restrict__ ws,
    const float* __restrict__ outLs,
    const float* __restrict__ treeL,
    const float* __restrict__ treeR,
    const float* __restrict__ treeLb,
    const float* __restrict__ treeRb,
    float* __restrict__ out)
{
    __shared__ floatx4 st[256 * 8];   // 32 KiB
    const int tid = threadIdx.x;
    const unsigned B = blockIdx.x * 256u + tid;
    const float* C16 = ws + C16OFF;

    float acc[32];
    {   // C16 row (contiguous 128 B, 16B-aligned)
        const floatx4* c4 = (const floatx4*)(C16 + (size_t)(B & 0x1FFFFu) * 32);
        #pragma unroll
        for (int q = 0; q < 8; ++q) {
            floatx4 v = c4[q];
            acc[q * 4 + 0] = v.x; acc[q * 4 + 1] = v.y;
            acc[q * 4 + 2] = v.z; acc[q * 4 + 3] = v.w;
        }
    }

    // levels 17..20: two register chains from the two level-16 ancestor rows
    {
        const unsigned Blo = B & 0xFFFFu;
        const float* r16 = ws + ((1u << 18) - 4);
        float2 vA = *(const float2*)(r16 + Blo * 2);
        float2 vC = *(const float2*)(r16 + (Blo + 65536u) * 2);
        float A0 = vA.x, A1 = vA.y;   // MSB=0 chain
        float c0 = vC.x, c1 = vC.y;   // MSB=1 chain
        #pragma unroll
        for (int l = 17; l <= 20; ++l) {
            const int s = (B >> (l - 1)) & 1;
            const float* WL = treeL  + (l - 1) * 4;   // uniform -> scalar loads
            const float* WR = treeR  + (l - 1) * 4;
            const float* bL = treeLb + (l - 1) * 2;
            const float* bR = treeRb + (l - 1) * 2;
            const float w00 = s ? WR[0] : WL[0], w01 = s ? WR[1] : WL[1];
            const float w10 = s ? WR[2] : WL[2], w11 = s ? WR[3] : WL[3];
            const float b0  = s ? bR[0] : bL[0], b1  = s ? bR[1] : bL[1];
            const float nA0 = w00 * A0 + w01 * A1 + b0;
            const float nA1 = w10 * A0 + w11 * A1 + b1;
            const float nc0 = w00 * c0 + w01 * c1 + b0;
            const float nc1 = w10 * c0 + w11 * c1 + b1;
            A0 = nA0; A1 = nA1; c0 = nc0; c1 = nc1;
            const int pick = (B >> l) & 1;
            const float q0 = pick ? c0 : A0, q1 = pick ? c1 : A1;
            const float* cf = outLs + l * 64;
            #pragma unroll
            for (int o = 0; o < 32; ++o)
                acc[o] += q0 * cf[o * 2] + q1 * cf[o * 2 + 1];
        }
    }

    // ---- transpose through LDS, then fully-coalesced 1 KiB/instr nt stores --
    #pragma unroll
    for (int q = 0; q < 8; ++q) {
        st[tid * 8 + (q ^ (tid & 7))] =
            (floatx4){acc[q * 4 + 0], acc[q * 4 + 1],
                      acc[q * 4 + 2], acc[q * 4 + 3]};
    }
    __syncthreads();
    {
        const int w = tid >> 6, lane = tid & 63;
        const int x = (lane & 7) ^ (lane >> 3);
        floatx4* dst = (floatx4*)(out + (size_t)blockIdx.x * 8192u
                                      + (unsigned)w * 2048u + (unsigned)lane * 4u);
        #pragma unroll
        for (int j = 0; j < 8; ++j) {
            const int m = w * 64 + j * 8 + (lane >> 3);
            __builtin_nontemporal_store(st[m * 8 + x], dst + j * 64);
        }
    }
}

// ======================= legacy fallback chain (R4-verified) =================
__global__ __launch_bounds__(1024) void k_levels(
    const float* __restrict__ inLb,
    const float* __restrict__ inRb,
    const float* __restrict__ treeL,
    const float* __restrict__ treeR,
    const float* __restrict__ treeLb,
    const float* __restrict__ treeRb,
    const float* __restrict__ outLs,
    const float* __restrict__ outB,
    float* __restrict__ ws)
{
    const int tid = threadIdx.x;
    float* base  = ws + P0;
    float* outLf = ws + P0 + 32;
    float* tLf   = ws + P0 + 1376;
    float* tRf   = ws + P0 + 1460;
    float* tLbf  = ws + P0 + 1544;
    float* tRbf  = ws + P0 + 1586;
    const float* dots = ws + P0 + 1664;
    float* C7    = ws + P0 + 2048;

    for (int i = tid; i < 21 * 64; i += 1024) outLf[i] = outLs[i];
    if (tid < 84)                      tLf[tid]        = treeL[tid];
    else if (tid < 168)                tRf[tid - 84]   = treeR[tid - 84];
    else if (tid < 210)                tLbf[tid - 168] = treeLb[tid - 168];
    else if (tid < 252)                tRbf[tid - 210] = treeRb[tid - 210];
    if (tid < 32) base[tid] = dots[4 + tid] + outB[tid];
    if (tid < 2) {
        ws[tid * 2 + 0] = dots[tid]     + inLb[tid];
        ws[tid * 2 + 1] = dots[2 + tid] + inRb[tid];
    }
    __syncthreads();

    for (int i = 1; i <= 13; ++i) {
        const float* prev = ws + ((1u << (i + 1)) - 4);
        float* cur        = ws + ((1u << (i + 2)) - 4);
        const int rows = 1 << (i + 1);
        const int lowmask = (1 << (i - 1)) - 1;
        for (int m = tid; m < rows; m += 1024) {
            const int src = ((m >> i) << (i - 1)) | (m & lowmask);
            const int s = (m >> (i - 1)) & 1;
            const float* W  = (s ? tRf  : tLf)  + (i - 1) * 4;
            const float* bb = (s ? tRbf : tLbf) + (i - 1) * 2;
            const float p0 = prev[src * 2], p1 = prev[src * 2 + 1];
            cur[m * 2 + 0] = W[0] * p0 + W[1] * p1 + bb[0];
            cur[m * 2 + 1] = W[2] * p0 + W[3] * p1 + bb[1];
        }
        __syncthreads();
    }

    for (int idx = tid; idx < 8192; idx += 1024) {
        const int m = idx >> 5, o = idx & 31;
        float s = base[o];
        #pragma unroll
        for (int i = 0; i < 8; ++i) {
            const float* ri = ws + ((1u << (i + 2)) - 4) + (m & ((2 << i) - 1)) * 2;
            s += ri[0] * outLf[i * 64 + o * 2] + ri[1] * outLf[i * 64 + o * 2 + 1];
        }
        C7[idx] = s;
    }
}

__global__ __launch_bounds__(256) void k_mid(float* __restrict__ ws)
{
    const int blk = blockIdx.x;
    int j, b;
    if      (blk < 16) { j = 14; b = blk; }
    else if (blk < 48) { j = 15; b = blk - 16; }
    else               { j = 16; b = blk - 48; }

    const float* tLf  = ws + P0 + 1376;
    const float* tRf  = ws + P0 + 1460;
    const float* tLbf = ws + P0 + 1544;
    const float* tRbf = ws + P0 + 1586;

    unsigned m = (unsigned)b << 11;
    const unsigned basej = m;
    unsigned sbits = 0;
    for (int l = j; l > 13; --l) {
        sbits |= ((m >> (l - 1)) & 1u) << l;
        m = ((m >> l) << (l - 1)) | (m & ((1u << (l - 1)) - 1));
    }

    const int r0 = threadIdx.x * 8;
    const floatx4* s4 = (const floatx4*)(ws + ((1u << 15) - 4) + (m + r0) * 2);
    floatx4 a0 = s4[0], a1 = s4[1], a2 = s4[2], a3 = s4[3];
    float r[8][2] = {{a0.x,a0.y},{a0.z,a0.w},{a1.x,a1.y},{a1.z,a1.w},
                     {a2.x,a2.y},{a2.z,a2.w},{a3.x,a3.y},{a3.z,a3.w}};

    for (int l = 14; l <= j; ++l) {
        const int s = (sbits >> l) & 1;
        const float* W  = (s ? tRf  : tLf)  + (l - 1) * 4;
        const float* bb = (s ? tRbf : tLbf) + (l - 1) * 2;
        const float w00 = W[0], w01 = W[1], w10 = W[2], w11 = W[3];
        const float b0 = bb[0], b1 = bb[1];
        #pragma unroll
        for (int q = 0; q < 8; ++q) {
            const float p0 = r[q][0], p1 = r[q][1];
            r[q][0] = w00 * p0 + w01 * p1 + b0;
            r[q][1] = w10 * p0 + w11 * p1 + b1;
        }
    }

    floatx4* d4 = (floatx4*)(ws + ((1u << (j + 2)) - 4) + (basej + r0) * 2);
    d4[0] = (floatx4){r[0][0], r[0][1], r[1][0], r[1][1]};
    d4[1] = (floatx4){r[2][0], r[2][1], r[3][0], r[3][1]};
    d4[2] = (floatx4){r[4][0], r[4][1], r[5][0], r[5][1]};
    d4[3] = (floatx4){r[6][0], r[6][1], r[7][0], r[7][1]};
}

__global__ __launch_bounds__(256) void k_c14(float* __restrict__ ws)
{
    const unsigned m = blockIdx.x * 256u + threadIdx.x;
    const float* outLf = ws + P0 + 32;
    const float* C7    = ws + P0 + 2048;

    float acc[32];
    const floatx4* c4 = (const floatx4*)(C7 + (m & 255u) * 32);
    #pragma unroll
    for (int q = 0; q < 8; ++q) {
        floatx4 v = c4[q];
        acc[q * 4 + 0] = v.x; acc[q * 4 + 1] = v.y;
        acc[q * 4 + 2] = v.z; acc[q * 4 + 3] = v.w;
    }
    #pragma unroll
    for (int i = 8; i <= 14; ++i) {
        const float2 v = *(const float2*)(ws + ((1u << (i + 2)) - 4)
                                             + (m & ((2u << i) - 1)) * 2);
        const float* cf = outLf + i * 64;
        #pragma unroll
        for (int o = 0; o < 32; ++o)
            acc[o] += v.x * cf[o * 2] + v.y * cf[o * 2 + 1];
    }
    floatx4* dst = (floatx4*)(ws + C14OFF + m * 32);
    #pragma unroll
    for (int q = 0; q < 8; ++q)
        dst[q] = (floatx4){acc[q * 4 + 0], acc[q * 4 + 1],
                           acc[q * 4 + 2], acc[q * 4 + 3]};
}

__global__ __launch_bounds__(256) void k_final_fold(const float* __restrict__ ws,
                                                    float* __restrict__ out)
{
    __shared__ floatx4 st[256 * 8];
    const int tid = threadIdx.x;
    const unsigned B = blockIdx.x * 256u + tid;
    const float* outLf = ws + P0 + 32;
    const float* tLf   = ws + P0 + 1376;
    const float* tRf   = ws + P0 + 1460;
    const float* tLbf  = ws + P0 + 1544;
    const float* tRbf  = ws + P0 + 1586;
    const float* C14   = ws + C14OFF;

    float acc[32];
    {
        const floatx4* c4 = (const floatx4*)(C14 + (B & 0x7FFFu) * 32);
        #pragma unroll
        for (int q = 0; q < 8; ++q) {
            floatx4 v = c4[q];
            acc[q * 4 + 0] = v.x; acc[q * 4 + 1] = v.y;
            acc[q * 4 + 2] = v.z; acc[q * 4 + 3] = v.w;
        }
    }
    {
        const float2 v = *(const float2*)(ws + ((1u << 17) - 4)
                                             + (B & 0xFFFFu) * 2);
        const float* cf = outLf + 15 * 64;
        #pragma unroll
        for (int o = 0; o < 32; ++o)
            acc[o] += v.x * cf[o * 2] + v.y * cf[o * 2 + 1];
    }
    {
        const unsigned Blo = B & 0xFFFFu;
        const float* r16 = ws + ((1u << 18) - 4);
        float2 vA = *(const float2*)(r16 + Blo * 2);
        float2 vC = *(const float2*)(r16 + (Blo + 65536u) * 2);
        float A0 = vA.x, A1 = vA.y;
        float c0 = vC.x, c1 = vC.y;
        {
            const int pick = (B >> 16) & 1;
            const float q0 = pick ? c0 : A0, q1 = pick ? c1 : A1;
            const float* cf = outLf + 16 * 64;
            #pragma unroll
            for (int o = 0; o < 32; ++o)
                acc[o] += q0 * cf[o * 2] + q1 * cf[o * 2 + 1];
        }
        #pragma unroll
        for (int l = 17; l <= 20; ++l) {
            const int s = (B >> (l - 1)) & 1;
            const float* WL = tLf + (l - 1) * 4;
            const float* WR = tRf + (l - 1) * 4;
            const float* bL = tLbf + (l - 1) * 2;
            const float* bR = tRbf + (l - 1) * 2;
            const float w00 = s ? WR[0] : WL[0], w01 = s ? WR[1] : WL[1];
            const float w10 = s ? WR[2] : WL[2], w11 = s ? WR[3] : WL[3];
            const float b0  = s ? bR[0] : bL[0], b1  = s ? bR[1] : bL[1];
            const float nA0 = w00 * A0 + w01 * A1 + b0;
            const float nA1 = w10 * A0 + w11 * A1 + b1;
            const float nc0 = w00 * c0 + w01 * c1 + b0;
            const float nc1 = w10 * c0 + w11 * c1 + b1;
            A0 = nA0; A1 = nA1; c0 = nc0; c1 = nc1;
            const int pick = (B >> l) & 1;
            const float q0 = pick ? c0 : A0, q1 = pick ? c1 : A1;
            const float* cf = outLf + l * 64;
            #pragma unroll
            for (int o = 0; o < 32; ++o)
                acc[o] += q0 * cf[o * 2] + q1 * cf[o * 2 + 1];
        }
    }
    #pragma unroll
    for (int q = 0; q < 8; ++q) {
        st[tid * 8 + (q ^ (tid & 7))] =
            (floatx4){acc[q * 4 + 0], acc[q * 4 + 1],
                      acc[q * 4 + 2], acc[q * 4 + 3]};
    }
    __syncthreads();
    {
        const int w = tid >> 6, lane = tid & 63;
        const int x = (lane & 7) ^ (lane >> 3);
        floatx4* dst = (floatx4*)(out + (size_t)blockIdx.x * 8192u
                                      + (unsigned)w * 2048u + (unsigned)lane * 4u);
        #pragma unroll
        for (int j = 0; j < 8; ++j) {
            const int m = w * 64 + j * 8 + (lane >> 3);
            __builtin_nontemporal_store(st[m * 8 + x], dst + j * 64);
        }
    }
}

__global__ __launch_bounds__(256) void k_final_legacy(const float* __restrict__ ws,
                                                      float* __restrict__ out)
{
    __shared__ floatx4 st[256 * 8];
    const int tid = threadIdx.x;
    const unsigned B = blockIdx.x * 256u + tid;
    const float* outLf = ws + P0 + 32;
    const float* tLf   = ws + P0 + 1376;
    const float* tRf   = ws + P0 + 1460;
    const float* tLbf  = ws + P0 + 1544;
    const float* tRbf  = ws + P0 + 1586;
    const float* C7    = ws + P0 + 2048;

    float acc[32];
    {
        const floatx4* c4 = (const floatx4*)(C7 + (B & 255u) * 32);
        #pragma unroll
        for (int q = 0; q < 8; ++q) {
            floatx4 v = c4[q];
            acc[q * 4 + 0] = v.x; acc[q * 4 + 1] = v.y;
            acc[q * 4 + 2] = v.z; acc[q * 4 + 3] = v.w;
        }
    }
    float p[8][2];
    #pragma unroll
    for (int i = 8; i <= 15; ++i) {
        const float2* ri = (const float2*)(ws + ((1u << (i + 2)) - 4)
                                              + (B & ((2u << i) - 1)) * 2);
        float2 v = *ri;
        p[i - 8][0] = v.x;
        p[i - 8][1] = v.y;
    }
    #pragma unroll
    for (int i = 0; i < 8; ++i) {
        const float* cf = outLf + (i + 8) * 64;
        const float q0 = p[i][0], q1 = p[i][1];
        #pragma unroll
        for (int o = 0; o < 32; ++o)
            acc[o] += q0 * cf[o * 2] + q1 * cf[o * 2 + 1];
    }
    {
        const unsigned Blo = B & 0xFFFFu;
        const float* r16 = ws + ((1u << 18) - 4);
        float2 vA = *(const float2*)(r16 + Blo * 2);
        float2 vC = *(const float2*)(r16 + (Blo + 65536u) * 2);
        float A0 = vA.x, A1 = vA.y;
        float c0 = vC.x, c1 = vC.y;
        {
            const int pick = (B >> 16) & 1;
            const float q0 = pick ? c0 : A0, q1 = pick ? c1 : A1;
            const float* cf = outLf + 16 * 64;
            #pragma unroll
            for (int o = 0; o < 32; ++o)
                acc[o] += q0 * cf[o * 2] + q1 * cf[o * 2 + 1];
        }
        #pragma unroll
        for (int l = 17; l <= 20; ++l) {
            const int s = (B >> (l - 1)) & 1;
            const float* WL = tLf + (l - 1) * 4;
            const float* WR = tRf + (l - 1) * 4;
            const float* bL = tLbf + (l - 1) * 2;
            const float* bR = tRbf + (l - 1) * 2;
            const float w00 = s ? WR[0] : WL[0], w01 = s ? WR[1] : WL[1];
            const float w10 = s ? WR[2] : WL[2], w11 = s ? WR[3] : WL[3];
            const float b0  = s ? bR[0] : bL[0], b1  = s ? bR[1] : bL[1];
            const float nA0 = w00 * A0 + w01 * A1 + b0;
            const float nA1 = w10 * A0 + w11 * A1 + b1;
            const float nc0 = w00 * c0 + w01 * c1 + b0;
            const float nc1 = w10 * c0 + w11 * c1 + b1;
            A0 = nA0; A1 = nA1; c0 = nc0; c1 = nc1;
            const int pick = (B >> l) & 1;
            const float q0 = pick ? c0 : A0, q1 = pick ? c1 : A1;
            const float* cf = outLf + l * 64;
            #pragma unroll
            for (int o = 0; o < 32; ++o)
                acc[o] += q0 * cf[o * 2] + q1 * cf[o * 2 + 1];
        }
    }
    #pragma unroll
    for (int q = 0; q < 8; ++q) {
        st[tid * 8 + (q ^ (tid & 7))] =
            (floatx4){acc[q * 4 + 0], acc[q * 4 + 1],
                      acc[q * 4 + 2], acc[q * 4 + 3]};
    }
    __syncthreads();
    {
        const int w = tid >> 6, lane = tid & 63;
        const int x = (lane & 7) ^ (lane >> 3);
        floatx4* dst = (floatx4*)(out + (size_t)blockIdx.x * 8192u
                                      + (unsigned)w * 2048u + (unsigned)lane * 4u);
        #pragma unroll
        for (int j = 0; j < 8; ++j) {
            const int m = w * 64 + j * 8 + (lane >> 3);
            __builtin_nontemporal_store(st[m * 8 + x], dst + j * 64);
        }
    }
}

extern "C" void kernel_launch(void* const* d_in, const int* in_sizes, int n_in,
                              void* d_out, int out_size, void* d_ws, size_t ws_size,
                              hipStream_t stream) {
    const float* x     = (const float*)d_in[0];
    const float* inL   = (const float*)d_in[1];
    const float* inR   = (const float*)d_in[2];
    const float* inLb  = (const float*)d_in[3];
    const float* inRb  = (const float*)d_in[4];
    const float* treeL = (const float*)d_in[5];
    const float* treeR = (const float*)d_in[6];
    const float* treeLb= (const float*)d_in[7];
    const float* treeRb= (const float*)d_in[8];
    const float* outL0 = (const float*)d_in[9];
    const float* outLs = (const float*)d_in[10];
    const float* outB  = (const float*)d_in[11];
    float* ws = (float*)d_ws;
    float* out = (float*)d_out;

    const bool use_c16 = ws_size >= ((size_t)C16OFF + (1u << 22)) * sizeof(float); // 24 MB
    const bool use_c14 = ws_size >= ((size_t)C14OFF + (1u << 20)) * sizeof(float); //  8 MB

    hipLaunchKernelGGL(k_dots, dim3(36), dim3(1024), 0, stream,
                       x, inL, inR, outL0, ws);
    if (use_c16) {
        hipLaunchKernelGGL(k_paths, dim3(1024), dim3(256), 0, stream,
                           treeL, treeR, treeLb, treeRb, inLb, inRb, ws);
        hipLaunchKernelGGL(k_c16f, dim3(512), dim3(256), 0, stream,
                           outLs, outB, ws);
        hipLaunchKernelGGL(k_final_c16, dim3(1u << 13), dim3(256), 0, stream,
                           ws, outLs, treeL, treeR, treeLb, treeRb, out);
    } else {
        hipLaunchKernelGGL(k_levels, dim3(1), dim3(1024), 0, stream,
                           inLb, inRb, treeL, treeR, treeLb, treeRb, outLs, outB, ws);
        hipLaunchKernelGGL(k_mid, dim3(112), dim3(256), 0, stream, ws);
        if (use_c14) {
            hipLaunchKernelGGL(k_c14, dim3(128), dim3(256), 0, stream, ws);
            hipLaunchKernelGGL(k_final_fold, dim3(1u << 13), dim3(256), 0, stream, ws, out);
        } else {
            hipLaunchKernelGGL(k_final_legacy, dim3(1u << 13), dim3(256), 0, stream, ws, out);
        }
    }
}